// Round 3
// baseline (402.519 us; speedup 1.0000x reference)
//
#include <hip/hip_runtime.h>
#include <hip/hip_bf16.h>
#include <stdint.h>

// Problem dims (fixed by setup_inputs)
#define M_TOTAL 2048     // B (feats rows)
#define N_TOTAL 16384    // Bs*TOPK (support rows)
#define K_TOTAL 2048     // C
#define NPARTS  256      // 128 n-tiles * 2 n-waves

// Uniform MX scale: stored_fp8 = value * 2^9, HW dequant scale = 2^-9 per operand.
// e8m0 byte = 127 - 9 = 118 = 0x76. Uniform bytes -> immune to scale-lane layout.
#define SCALE_E8M0 0x76767676
#define SCALE_F 512.0f

typedef __attribute__((ext_vector_type(8))) int   int8v;    // 32B fp8 MFMA A/B frag
typedef __attribute__((ext_vector_type(4))) float floatx4;  // MFMA C/D frag

// ---------------------------------------------------------------- fp32 -> fp8 e4m3 (scaled)
__global__ void cvt_fp8(const float4* __restrict__ src, uint32_t* __restrict__ dst, int n4) {
    int i = blockIdx.x * blockDim.x + threadIdx.x;
    const int stride = gridDim.x * blockDim.x;
    for (; i < n4; i += stride) {
        float4 v = src[i];
        int p = __builtin_amdgcn_cvt_pk_fp8_f32(v.x * SCALE_F, v.y * SCALE_F, 0, 0);
        p = __builtin_amdgcn_cvt_pk_fp8_f32(v.z * SCALE_F, v.w * SCALE_F, p, 1);
        dst[i] = (uint32_t)p;
    }
}

// ---------------------------------------------------------------- GEMM + fused epilogue
__device__ __forceinline__ void load16(const void* g, void* l) {
    __builtin_amdgcn_global_load_lds(
        (const __attribute__((address_space(1))) void*)g,
        (__attribute__((address_space(3))) void*)l, 16, 0, 0);
}

// LDS tile: 128 rows x 128 B (K=128 fp8). 16B chunk at global k-pos q lives at
// physical pos p = q ^ (((row>>1)&3)<<1)  (bit0 preserved -> each lane's 32B
// frag stays contiguous; quarter-wave frag reads spread 4-way instead of 16-way).
// Swizzle applied on the GLOBAL address side of global_load_lds.
__global__ __launch_bounds__(256) void gemm_lp(
        const char* __restrict__ Af8, const char* __restrict__ Bf8,
        const int* __restrict__ labels, const int* __restrict__ labels_s,
        float* __restrict__ pminp, float* __restrict__ psump) {
    __shared__ __align__(16) char lsA[128 * 128];
    __shared__ __align__(16) char lsB[128 * 128];
    __shared__ int lab_m[128];
    __shared__ int lab_n[128];

    const int t    = threadIdx.x;
    const int lane = t & 63;
    const int wave = t >> 6;
    const int wm   = wave >> 1;   // row half (0..1)
    const int wn   = wave & 1;    // col half (0..1)
    const int m0   = blockIdx.y * 128;
    const int n0   = blockIdx.x * 128;

    if (t < 128) lab_m[t] = labels[m0 + t];
    else         lab_n[t - 128] = labels_s[n0 + t - 128];

    // staging: issue j (0..3) per matrix; thread t fills phys chunk c = j*256+t.
    // phys row = j*32 + (t>>3); global 16B k-chunk q = (t&7) ^ (((t>>4)&3)<<1)
    // (j-independent since j*32 rows shift (row>>1)&3 by multiples of 4).
    const int rq = t >> 3;                                  // row within 32-row group
    const int qt = (t & 7) ^ (((t >> 4) & 3) << 1);         // swizzled k-chunk
    const long aBase = (long)(m0 + rq) * K_TOTAL + qt * 16;
    const long bBase = (long)(n0 + rq) * K_TOTAL + qt * 16;
    char* lA = lsA + wave * 1024;            // wave-uniform LDS base; HW adds lane*16B
    char* lB = lsB + wave * 1024;

    // MFMA fragment pointers: lane reads 32B at row R, k-block quad:
    // byte off = R*128 + ((2*quad) ^ (((R>>1)&3)<<1))*16   (32B-aligned)
    const int quad = lane >> 4;
    const int lcol = lane & 15;
    const int8v* pa[4]; const int8v* pb[4];
#pragma unroll
    for (int i = 0; i < 4; ++i) {
        const int Ra = wm * 64 + i * 16 + lcol;
        const int Rb = wn * 64 + i * 16 + lcol;
        pa[i] = (const int8v*)(lsA + Ra * 128 + (((2 * quad) ^ (((Ra >> 1) & 3) << 1)) << 4));
        pb[i] = (const int8v*)(lsB + Rb * 128 + (((2 * quad) ^ (((Rb >> 1) & 3) << 1)) << 4));
    }

    floatx4 acc[4][4];
#pragma unroll
    for (int mi = 0; mi < 4; ++mi)
#pragma unroll
        for (int ni = 0; ni < 4; ++ni)
            acc[mi][ni] = (floatx4){0.f, 0.f, 0.f, 0.f};

    for (int kt = 0; kt < K_TOTAL / 128; ++kt) {            // 16 iterations
        const long ko = (long)kt * 128;
        __syncthreads();                         // previous iter's frag reads done
#pragma unroll
        for (int j = 0; j < 4; ++j) {
            load16(Af8 + aBase + (long)j * 32 * K_TOTAL + ko, lA + j * 4096);
            load16(Bf8 + bBase + (long)j * 32 * K_TOTAL + ko, lB + j * 4096);
        }
        __syncthreads();                         // drains vmcnt -> tiles ready
        int8v av[4], bv[4];
#pragma unroll
        for (int i = 0; i < 4; ++i) av[i] = *pa[i];
#pragma unroll
        for (int i = 0; i < 4; ++i) bv[i] = *pb[i];
#pragma unroll
        for (int mi = 0; mi < 4; ++mi)
#pragma unroll
            for (int ni = 0; ni < 4; ++ni)
                acc[mi][ni] = __builtin_amdgcn_mfma_scale_f32_16x16x128_f8f6f4(
                    av[mi], bv[ni], acc[mi][ni],
                    0, 0,                         // cbsz=fp8(e4m3), blgp=fp8(e4m3)
                    0, SCALE_E8M0,                // opsel_a, scale_a (2^-9 all bytes)
                    0, SCALE_E8M0);               // opsel_b, scale_b
    }

    // Epilogue: e = exp(sim/TEMP) = exp2(sim * 28.8539); masked min/sum over cols.
    // C/D layout (shape-determined): col = lane&15, row = quad*4 + reg
    const float scale = 28.853900817779268f;     // 20 * log2(e)
#pragma unroll
    for (int mi = 0; mi < 4; ++mi) {
#pragma unroll
        for (int r = 0; r < 4; ++r) {
            const int row_local = wm * 64 + mi * 16 + quad * 4 + r;
            const int lab = lab_m[row_local];
            float minv = __builtin_inff();
            float sumv = 0.f;
#pragma unroll
            for (int ni = 0; ni < 4; ++ni) {
                const int col_local = wn * 64 + ni * 16 + lcol;
                const float e = exp2f(acc[mi][ni][r] * scale);
                const bool pos = (lab_n[col_local] == lab);
                minv = pos ? fminf(minv, e) : minv;
                sumv = pos ? sumv : (sumv + e);
            }
#pragma unroll
            for (int off = 1; off < 16; off <<= 1) {
                minv = fminf(minv, __shfl_xor(minv, off, 16));
                sumv += __shfl_xor(sumv, off, 16);
            }
            if (lcol == 0) {
                // partials laid out [row][part] so reduce_rows reads coalesced
                const long idx = (long)(m0 + row_local) * NPARTS + blockIdx.x * 2 + wn;
                pminp[idx] = minv;
                psump[idx] = sumv;
            }
        }
    }
}

// ---------------------------------------------------------------- row fold + mean
// one wave per row, 512 blocks x 4 waves = 2048 waves
__global__ __launch_bounds__(256) void reduce_rows(
        const float* __restrict__ pminp, const float* __restrict__ psump,
        float* __restrict__ loss) {
    const int row  = blockIdx.x * 4 + (threadIdx.x >> 6);
    const int lane = threadIdx.x & 63;
    float m = __builtin_inff();
    float s = 0.f;
#pragma unroll
    for (int k = 0; k < NPARTS / 64; ++k) {
        const long j = (long)row * NPARTS + lane + k * 64;
        m = fminf(m, pminp[j]);
        s += psump[j];
    }
#pragma unroll
    for (int off = 1; off < 64; off <<= 1) {
        m = fminf(m, __shfl_xor(m, off, 64));
        s += __shfl_xor(s, off, 64);
    }
    if (lane == 0) loss[row] = -logf(m / (m + s + 1e-6f) + 1e-6f);
}

__global__ void final_mean(const float* __restrict__ loss, float* __restrict__ out) {
    float s = 0.f;
    for (int i = threadIdx.x; i < M_TOTAL; i += 256) s += loss[i];
#pragma unroll
    for (int off = 32; off > 0; off >>= 1) s += __shfl_xor(s, off, 64);
    __shared__ float wsum[4];
    if ((threadIdx.x & 63) == 0) wsum[threadIdx.x >> 6] = s;
    __syncthreads();
    if (threadIdx.x == 0)
        out[0] = (wsum[0] + wsum[1] + wsum[2] + wsum[3]) * (1.0f / (float)M_TOTAL);
}

// ---------------------------------------------------------------- launcher
extern "C" void kernel_launch(void* const* d_in, const int* in_sizes, int n_in,
                              void* d_out, int out_size, void* d_ws, size_t ws_size,
                              hipStream_t stream) {
    const float* feats    = (const float*)d_in[0];
    const float* feats_s  = (const float*)d_in[1];
    const int*   labels   = (const int*)d_in[2];
    const int*   labels_s = (const int*)d_in[3];
    float*       out      = (float*)d_out;

    char* ws = (char*)d_ws;
    char*  Af8   = ws;                                    //  4,194,304 B
    char*  Bf8   = ws + 4194304;                          // 33,554,432 B
    float* pminp = (float*)(ws + 37748736);               //  2,097,152 B
    float* psump = (float*)(ws + 39845888);               //  2,097,152 B
    float* loss  = (float*)(ws + 41943040);               //      8,192 B

    cvt_fp8<<<512,  256, 0, stream>>>((const float4*)feats,   (uint32_t*)Af8,
                                      M_TOTAL * K_TOTAL / 4);
    cvt_fp8<<<2048, 256, 0, stream>>>((const float4*)feats_s, (uint32_t*)Bf8,
                                      N_TOTAL * K_TOTAL / 4);

    dim3 grid(N_TOTAL / 128, M_TOTAL / 128);              // 128 x 16
    gemm_lp<<<grid, 256, 0, stream>>>(Af8, Bf8, labels, labels_s, pminp, psump);

    reduce_rows<<<512, 256, 0, stream>>>(pminp, psump, loss);
    final_mean<<<1, 256, 0, stream>>>(loss, out);
}

// Round 4
// 398.035 us; speedup vs baseline: 1.0113x; 1.0113x over previous
//
#include <hip/hip_runtime.h>
#include <hip/hip_bf16.h>
#include <stdint.h>

// Problem dims (fixed by setup_inputs)
#define M_TOTAL 2048     // B (feats rows)
#define N_TOTAL 16384    // Bs*TOPK (support rows)
#define K_TOTAL 2048     // C
#define NPARTS  256      // 128 n-tiles * 2 n-waves

// Uniform MX scale: stored_fp8 = value * 2^9, HW dequant scale = 2^-9 per operand.
// e8m0 byte = 127 - 9 = 118 = 0x76. Uniform bytes -> immune to scale-lane layout.
#define SCALE_E8M0 0x76767676
#define SCALE_F 512.0f

typedef __attribute__((ext_vector_type(4))) int   int4v;    // 16B (one ds_read_b128)
typedef __attribute__((ext_vector_type(8))) int   int8v;    // 32B fp8 MFMA A/B frag
typedef __attribute__((ext_vector_type(4))) float floatx4;  // MFMA C/D frag

// ---------------------------------------------------------------- fp32 -> fp8 e4m3 (scaled)
__global__ void cvt_fp8(const float4* __restrict__ src, uint32_t* __restrict__ dst, int n4) {
    int i = blockIdx.x * blockDim.x + threadIdx.x;
    const int stride = gridDim.x * blockDim.x;
    for (; i < n4; i += stride) {
        float4 v = src[i];
        int p = __builtin_amdgcn_cvt_pk_fp8_f32(v.x * SCALE_F, v.y * SCALE_F, 0, 0);
        p = __builtin_amdgcn_cvt_pk_fp8_f32(v.z * SCALE_F, v.w * SCALE_F, p, 1);
        dst[i] = (uint32_t)p;
    }
}

// ---------------------------------------------------------------- GEMM + fused epilogue
__device__ __forceinline__ void load16(const void* g, void* l) {
    __builtin_amdgcn_global_load_lds(
        (const __attribute__((address_space(1))) void*)g,
        (__attribute__((address_space(3))) void*)l, 16, 0, 0);
}

// LDS tile: 128 rows x 128 B (K=128 fp8). 16B chunk at global k-pos q of row R
// lives at phys pos p = q ^ (R & 7)  (full 3-bit XOR). Fragment loads are TWO
// independent ds_read_b128 per 32B operand; within a quarter-wave (fixed quad,
// lcol=0..15, R&7 = lcol&7) the 16 lanes spread over all 8 bank-groups -> 2-way
// aliasing only (free). Swizzle applied on the GLOBAL address side of
// global_load_lds (LDS dest must remain wave-base + lane*16B).
__global__ __launch_bounds__(256) void gemm_lp(
        const char* __restrict__ Af8, const char* __restrict__ Bf8,
        const int* __restrict__ labels, const int* __restrict__ labels_s,
        float* __restrict__ pminp, float* __restrict__ psump) {
    __shared__ __align__(16) char lsA[128 * 128];
    __shared__ __align__(16) char lsB[128 * 128];
    __shared__ int lab_m[128];
    __shared__ int lab_n[128];

    const int t    = threadIdx.x;
    const int lane = t & 63;
    const int wave = t >> 6;
    const int wm   = wave >> 1;   // row half (0..1)
    const int wn   = wave & 1;    // col half (0..1)
    const int m0   = blockIdx.y * 128;
    const int n0   = blockIdx.x * 128;

    if (t < 128) lab_m[t] = labels[m0 + t];
    else         lab_n[t - 128] = labels_s[n0 + t - 128];

    // staging: issue j (0..3) per matrix; thread t fills phys chunk c = j*256+t.
    // phys row = j*32 + (t>>3), phys pos = t&7  ->  global 16B k-chunk
    // q = (t&7) ^ ((t>>3)&7)   (row&7 = (t>>3)&7, j-independent).
    const int rq = t >> 3;                                  // row within 32-row group
    const int qt = (t & 7) ^ ((t >> 3) & 7);                // swizzled k-chunk
    const long aBase = (long)(m0 + rq) * K_TOTAL + qt * 16;
    const long bBase = (long)(n0 + rq) * K_TOTAL + qt * 16;
    char* lA = lsA + wave * 1024;            // wave-uniform LDS base; HW adds lane*16B
    char* lB = lsB + wave * 1024;

    // Fragment read offsets: row R, k-chunks {2q, 2q+1} at phys pos (k ^ (lcol&7))
    // (R&7 == lcol&7 since wm*64 and i*16 are multiples of 8).
    const int quad = lane >> 4;
    const int lcol = lane & 15;
    const int plo = ((2 * quad) ^ (lcol & 7)) << 4;
    const int phi = ((2 * quad + 1) ^ (lcol & 7)) << 4;
    const char* paLo[4]; const char* paHi[4];
    const char* pbLo[4]; const char* pbHi[4];
#pragma unroll
    for (int i = 0; i < 4; ++i) {
        const int Ra = wm * 64 + i * 16 + lcol;
        const int Rb = wn * 64 + i * 16 + lcol;
        paLo[i] = lsA + Ra * 128 + plo;  paHi[i] = lsA + Ra * 128 + phi;
        pbLo[i] = lsB + Rb * 128 + plo;  pbHi[i] = lsB + Rb * 128 + phi;
    }

    floatx4 acc[4][4];
#pragma unroll
    for (int mi = 0; mi < 4; ++mi)
#pragma unroll
        for (int ni = 0; ni < 4; ++ni)
            acc[mi][ni] = (floatx4){0.f, 0.f, 0.f, 0.f};

    for (int kt = 0; kt < K_TOTAL / 128; ++kt) {            // 16 iterations
        const long ko = (long)kt * 128;
        __syncthreads();                         // previous iter's frag reads done
#pragma unroll
        for (int j = 0; j < 4; ++j) {
            load16(Af8 + aBase + (long)j * 32 * K_TOTAL + ko, lA + j * 4096);
            load16(Bf8 + bBase + (long)j * 32 * K_TOTAL + ko, lB + j * 4096);
        }
        __syncthreads();                         // drains vmcnt -> tiles ready

        // Hold all 4 B-frags (32 VGPRs); load A-frags one at a time (8 VGPRs)
        // to keep total live regs ~104 + addressing -> no spills.
        int8v bv[4];
#pragma unroll
        for (int i = 0; i < 4; ++i) {
            int4v lo = *(const int4v*)pbLo[i];
            int4v hi = *(const int4v*)pbHi[i];
            bv[i] = (int8v){lo.x, lo.y, lo.z, lo.w, hi.x, hi.y, hi.z, hi.w};
        }
#pragma unroll
        for (int mi = 0; mi < 4; ++mi) {
            int4v lo = *(const int4v*)paLo[mi];
            int4v hi = *(const int4v*)paHi[mi];
            int8v av = (int8v){lo.x, lo.y, lo.z, lo.w, hi.x, hi.y, hi.z, hi.w};
#pragma unroll
            for (int ni = 0; ni < 4; ++ni)
                acc[mi][ni] = __builtin_amdgcn_mfma_scale_f32_16x16x128_f8f6f4(
                    av, bv[ni], acc[mi][ni],
                    0, 0,                         // cbsz=fp8(e4m3), blgp=fp8(e4m3)
                    0, SCALE_E8M0,                // opsel_a, scale_a (2^-9 all bytes)
                    0, SCALE_E8M0);               // opsel_b, scale_b
        }
    }

    // Epilogue: e = exp(sim/TEMP) = exp2(sim * 28.8539); masked min/sum over cols.
    // C/D layout (shape-determined): col = lane&15, row = quad*4 + reg
    const float scale = 28.853900817779268f;     // 20 * log2(e)
#pragma unroll
    for (int mi = 0; mi < 4; ++mi) {
#pragma unroll
        for (int r = 0; r < 4; ++r) {
            const int row_local = wm * 64 + mi * 16 + quad * 4 + r;
            const int lab = lab_m[row_local];
            float minv = __builtin_inff();
            float sumv = 0.f;
#pragma unroll
            for (int ni = 0; ni < 4; ++ni) {
                const int col_local = wn * 64 + ni * 16 + lcol;
                const float e = exp2f(acc[mi][ni][r] * scale);
                const bool pos = (lab_n[col_local] == lab);
                minv = pos ? fminf(minv, e) : minv;
                sumv = pos ? sumv : (sumv + e);
            }
#pragma unroll
            for (int off = 1; off < 16; off <<= 1) {
                minv = fminf(minv, __shfl_xor(minv, off, 16));
                sumv += __shfl_xor(sumv, off, 16);
            }
            if (lcol == 0) {
                // partials laid out [row][part] so reduce_rows reads coalesced
                const long idx = (long)(m0 + row_local) * NPARTS + blockIdx.x * 2 + wn;
                pminp[idx] = minv;
                psump[idx] = sumv;
            }
        }
    }
}

// ---------------------------------------------------------------- row fold + mean
// one wave per row, 512 blocks x 4 waves = 2048 waves
__global__ __launch_bounds__(256) void reduce_rows(
        const float* __restrict__ pminp, const float* __restrict__ psump,
        float* __restrict__ loss) {
    const int row  = blockIdx.x * 4 + (threadIdx.x >> 6);
    const int lane = threadIdx.x & 63;
    float m = __builtin_inff();
    float s = 0.f;
#pragma unroll
    for (int k = 0; k < NPARTS / 64; ++k) {
        const long j = (long)row * NPARTS + lane + k * 64;
        m = fminf(m, pminp[j]);
        s += psump[j];
    }
#pragma unroll
    for (int off = 1; off < 64; off <<= 1) {
        m = fminf(m, __shfl_xor(m, off, 64));
        s += __shfl_xor(s, off, 64);
    }
    if (lane == 0) loss[row] = -logf(m / (m + s + 1e-6f) + 1e-6f);
}

__global__ void final_mean(const float* __restrict__ loss, float* __restrict__ out) {
    float s = 0.f;
    for (int i = threadIdx.x; i < M_TOTAL; i += 256) s += loss[i];
#pragma unroll
    for (int off = 32; off > 0; off >>= 1) s += __shfl_xor(s, off, 64);
    __shared__ float wsum[4];
    if ((threadIdx.x & 63) == 0) wsum[threadIdx.x >> 6] = s;
    __syncthreads();
    if (threadIdx.x == 0)
        out[0] = (wsum[0] + wsum[1] + wsum[2] + wsum[3]) * (1.0f / (float)M_TOTAL);
}

// ---------------------------------------------------------------- launcher
extern "C" void kernel_launch(void* const* d_in, const int* in_sizes, int n_in,
                              void* d_out, int out_size, void* d_ws, size_t ws_size,
                              hipStream_t stream) {
    const float* feats    = (const float*)d_in[0];
    const float* feats_s  = (const float*)d_in[1];
    const int*   labels   = (const int*)d_in[2];
    const int*   labels_s = (const int*)d_in[3];
    float*       out      = (float*)d_out;

    char* ws = (char*)d_ws;
    char*  Af8   = ws;                                    //  4,194,304 B
    char*  Bf8   = ws + 4194304;                          // 33,554,432 B
    float* pminp = (float*)(ws + 37748736);               //  2,097,152 B
    float* psump = (float*)(ws + 39845888);               //  2,097,152 B
    float* loss  = (float*)(ws + 41943040);               //      8,192 B

    cvt_fp8<<<512,  256, 0, stream>>>((const float4*)feats,   (uint32_t*)Af8,
                                      M_TOTAL * K_TOTAL / 4);
    cvt_fp8<<<2048, 256, 0, stream>>>((const float4*)feats_s, (uint32_t*)Bf8,
                                      N_TOTAL * K_TOTAL / 4);

    dim3 grid(N_TOTAL / 128, M_TOTAL / 128);              // 128 x 16
    gemm_lp<<<grid, 256, 0, stream>>>(Af8, Bf8, labels, labels_s, pminp, psump);

    reduce_rows<<<512, 256, 0, stream>>>(pminp, psump, loss);
    final_mean<<<1, 256, 0, stream>>>(loss, out);
}

// Round 5
// 289.524 us; speedup vs baseline: 1.3903x; 1.3748x over previous
//
#include <hip/hip_runtime.h>
#include <hip/hip_bf16.h>
#include <stdint.h>

// Problem dims (fixed by setup_inputs)
#define M_TOTAL 2048     // B (feats rows)
#define N_TOTAL 16384    // Bs*TOPK (support rows)
#define K_TOTAL 2048     // C
#define NPARTS  256      // 128 n-tiles * 2 n-waves

// Uniform MX scale: stored_fp8 = value * 2^9, HW dequant scale = 2^-9 per operand.
// e8m0 byte = 127 - 9 = 118 = 0x76. Uniform bytes -> immune to scale-lane layout.
#define SCALE_E8M0 0x76767676
#define SCALE_F 512.0f

typedef __attribute__((ext_vector_type(4))) int   int4v;    // 16B (one ds_read_b128)
typedef __attribute__((ext_vector_type(8))) int   int8v;    // 32B fp8 MFMA A/B frag
typedef __attribute__((ext_vector_type(4))) float floatx4;  // MFMA C/D frag

// ---------------------------------------------------------------- fp32 -> fp8 e4m3 (scaled)
__global__ void cvt_fp8(const float4* __restrict__ src, uint32_t* __restrict__ dst, int n4) {
    int i = blockIdx.x * blockDim.x + threadIdx.x;
    const int stride = gridDim.x * blockDim.x;
    for (; i < n4; i += stride) {
        float4 v = src[i];
        int p = __builtin_amdgcn_cvt_pk_fp8_f32(v.x * SCALE_F, v.y * SCALE_F, 0, 0);
        p = __builtin_amdgcn_cvt_pk_fp8_f32(v.z * SCALE_F, v.w * SCALE_F, p, 1);
        dst[i] = (uint32_t)p;
    }
}

// ---------------------------------------------------------------- GEMM + fused epilogue
__device__ __forceinline__ void load16(const void* g, void* l) {
    __builtin_amdgcn_global_load_lds(
        (const __attribute__((address_space(1))) void*)g,
        (__attribute__((address_space(3))) void*)l, 16, 0, 0);
}

// LDS tile: 128 rows x 128 B (K=128 fp8). 16B chunk at global k-pos q of row R
// lives at phys pos p = q ^ (R & 7). Fragment loads are two ds_read_b128 per
// 32B operand; quarter-wave lanes (R&7 = lcol&7) spread over all 8 bank-groups
// -> 2-way aliasing (free). Swizzle applied on the GLOBAL address side of
// global_load_lds (LDS dest must remain wave-base + lane*16B).
// K-loop is #pragma unroll 1: full unroll at trip-16 made the compiler keep
// 16 iterations of frag loads + pointers live -> 256 VGPR + scratch spills
// (rounds 3/4: WRITE_SIZE 110-135 MB of spill traffic).
__global__ __launch_bounds__(256) void gemm_lp(
        const char* __restrict__ Af8, const char* __restrict__ Bf8,
        const int* __restrict__ labels, const int* __restrict__ labels_s,
        float* __restrict__ pminp, float* __restrict__ psump) {
    __shared__ __align__(16) char lsA[128 * 128];
    __shared__ __align__(16) char lsB[128 * 128];
    __shared__ int lab_m[128];
    __shared__ int lab_n[128];

    const int t    = threadIdx.x;
    const int lane = t & 63;
    const int wave = t >> 6;
    const int wm   = wave >> 1;   // row half (0..1)
    const int wn   = wave & 1;    // col half (0..1)
    const int m0   = blockIdx.y * 128;
    const int n0   = blockIdx.x * 128;

    if (t < 128) lab_m[t] = labels[m0 + t];
    else         lab_n[t - 128] = labels_s[n0 + t - 128];

    // staging: issue j (0..3) per matrix; thread t fills phys chunk c = j*256+t.
    // phys row = j*32 + (t>>3), phys pos = t&7  ->  global 16B k-chunk
    // q = (t&7) ^ ((t>>3)&7)   (row&7 = (t>>3)&7, j-independent).
    const int rq = t >> 3;                                  // row within 32-row group
    const int qt = (t & 7) ^ ((t >> 3) & 7);                // swizzled k-chunk
    const char* aPtr = Af8 + (long)(m0 + rq) * K_TOTAL + qt * 16;
    const char* bPtr = Bf8 + (long)(n0 + rq) * K_TOTAL + qt * 16;
    char* lA = lsA + wave * 1024;            // wave-uniform LDS base; HW adds lane*16B
    char* lB = lsB + wave * 1024;

    // Fragment bases: row R = (wm|wn)*64 + lcol (+ mi*16), k-chunks {2q,2q+1} at
    // phys (k ^ (lcol&7)). The mi-step is +16 rows = +2048 B, mi-invariant in the
    // swizzle (R&7 == lcol&7) -> folds into the ds_read immediate offset.
    const int quad = lane >> 4;
    const int lcol = lane & 15;
    const int plo = ((2 * quad) ^ (lcol & 7)) << 4;
    const int phi = ((2 * quad + 1) ^ (lcol & 7)) << 4;
    const char* aLo = lsA + (wm * 64 + lcol) * 128 + plo;
    const char* aHi = lsA + (wm * 64 + lcol) * 128 + phi;
    const char* bLo = lsB + (wn * 64 + lcol) * 128 + plo;
    const char* bHi = lsB + (wn * 64 + lcol) * 128 + phi;

    floatx4 acc[4][4];
#pragma unroll
    for (int mi = 0; mi < 4; ++mi)
#pragma unroll
        for (int ni = 0; ni < 4; ++ni)
            acc[mi][ni] = (floatx4){0.f, 0.f, 0.f, 0.f};

#pragma unroll 1
    for (int kt = 0; kt < K_TOTAL / 128; ++kt) {            // 16 iterations, NOT unrolled
        __syncthreads();                         // previous iter's frag reads done
#pragma unroll
        for (int j = 0; j < 4; ++j) {
            load16(aPtr + j * 32 * K_TOTAL, lA + j * 4096);
            load16(bPtr + j * 32 * K_TOTAL, lB + j * 4096);
        }
        aPtr += 128;
        bPtr += 128;
        __syncthreads();                         // drains vmcnt -> tiles ready

        // Hold all 4 B-frags (32 VGPRs); stream A-frags one at a time (8 VGPRs).
        int8v bv[4];
#pragma unroll
        for (int i = 0; i < 4; ++i) {
            int4v lo = *(const int4v*)(bLo + i * 2048);
            int4v hi = *(const int4v*)(bHi + i * 2048);
            bv[i] = (int8v){lo.x, lo.y, lo.z, lo.w, hi.x, hi.y, hi.z, hi.w};
        }
#pragma unroll
        for (int mi = 0; mi < 4; ++mi) {
            int4v lo = *(const int4v*)(aLo + mi * 2048);
            int4v hi = *(const int4v*)(aHi + mi * 2048);
            int8v av = (int8v){lo.x, lo.y, lo.z, lo.w, hi.x, hi.y, hi.z, hi.w};
#pragma unroll
            for (int ni = 0; ni < 4; ++ni)
                acc[mi][ni] = __builtin_amdgcn_mfma_scale_f32_16x16x128_f8f6f4(
                    av, bv[ni], acc[mi][ni],
                    0, 0,                         // cbsz=fp8(e4m3), blgp=fp8(e4m3)
                    0, SCALE_E8M0,                // opsel_a, scale_a (2^-9 all bytes)
                    0, SCALE_E8M0);               // opsel_b, scale_b
        }
    }

    // Epilogue: e = exp(sim/TEMP) = exp2(sim * 28.8539); masked min/sum over cols.
    // C/D layout (shape-determined): col = lane&15, row = quad*4 + reg
    const float scale = 28.853900817779268f;     // 20 * log2(e)
#pragma unroll
    for (int mi = 0; mi < 4; ++mi) {
#pragma unroll
        for (int r = 0; r < 4; ++r) {
            const int row_local = wm * 64 + mi * 16 + quad * 4 + r;
            const int lab = lab_m[row_local];
            float minv = __builtin_inff();
            float sumv = 0.f;
#pragma unroll
            for (int ni = 0; ni < 4; ++ni) {
                const int col_local = wn * 64 + ni * 16 + lcol;
                const float e = exp2f(acc[mi][ni][r] * scale);
                const bool pos = (lab_n[col_local] == lab);
                minv = pos ? fminf(minv, e) : minv;
                sumv = pos ? sumv : (sumv + e);
            }
#pragma unroll
            for (int off = 1; off < 16; off <<= 1) {
                minv = fminf(minv, __shfl_xor(minv, off, 16));
                sumv += __shfl_xor(sumv, off, 16);
            }
            if (lcol == 0) {
                // partials laid out [row][part] so reduce_rows reads coalesced
                const long idx = (long)(m0 + row_local) * NPARTS + blockIdx.x * 2 + wn;
                pminp[idx] = minv;
                psump[idx] = sumv;
            }
        }
    }
}

// ---------------------------------------------------------------- row fold + mean
// one wave per row, 512 blocks x 4 waves = 2048 waves
__global__ __launch_bounds__(256) void reduce_rows(
        const float* __restrict__ pminp, const float* __restrict__ psump,
        float* __restrict__ loss) {
    const int row  = blockIdx.x * 4 + (threadIdx.x >> 6);
    const int lane = threadIdx.x & 63;
    float m = __builtin_inff();
    float s = 0.f;
#pragma unroll
    for (int k = 0; k < NPARTS / 64; ++k) {
        const long j = (long)row * NPARTS + lane + k * 64;
        m = fminf(m, pminp[j]);
        s += psump[j];
    }
#pragma unroll
    for (int off = 1; off < 64; off <<= 1) {
        m = fminf(m, __shfl_xor(m, off, 64));
        s += __shfl_xor(s, off, 64);
    }
    if (lane == 0) loss[row] = -logf(m / (m + s + 1e-6f) + 1e-6f);
}

__global__ void final_mean(const float* __restrict__ loss, float* __restrict__ out) {
    float s = 0.f;
    for (int i = threadIdx.x; i < M_TOTAL; i += 256) s += loss[i];
#pragma unroll
    for (int off = 32; off > 0; off >>= 1) s += __shfl_xor(s, off, 64);
    __shared__ float wsum[4];
    if ((threadIdx.x & 63) == 0) wsum[threadIdx.x >> 6] = s;
    __syncthreads();
    if (threadIdx.x == 0)
        out[0] = (wsum[0] + wsum[1] + wsum[2] + wsum[3]) * (1.0f / (float)M_TOTAL);
}

// ---------------------------------------------------------------- launcher
extern "C" void kernel_launch(void* const* d_in, const int* in_sizes, int n_in,
                              void* d_out, int out_size, void* d_ws, size_t ws_size,
                              hipStream_t stream) {
    const float* feats    = (const float*)d_in[0];
    const float* feats_s  = (const float*)d_in[1];
    const int*   labels   = (const int*)d_in[2];
    const int*   labels_s = (const int*)d_in[3];
    float*       out      = (float*)d_out;

    char* ws = (char*)d_ws;
    char*  Af8   = ws;                                    //  4,194,304 B
    char*  Bf8   = ws + 4194304;                          // 33,554,432 B
    float* pminp = (float*)(ws + 37748736);               //  2,097,152 B
    float* psump = (float*)(ws + 39845888);               //  2,097,152 B
    float* loss  = (float*)(ws + 41943040);               //      8,192 B

    cvt_fp8<<<512,  256, 0, stream>>>((const float4*)feats,   (uint32_t*)Af8,
                                      M_TOTAL * K_TOTAL / 4);
    cvt_fp8<<<2048, 256, 0, stream>>>((const float4*)feats_s, (uint32_t*)Bf8,
                                      N_TOTAL * K_TOTAL / 4);

    dim3 grid(N_TOTAL / 128, M_TOTAL / 128);              // 128 x 16
    gemm_lp<<<grid, 256, 0, stream>>>(Af8, Bf8, labels, labels_s, pminp, psump);

    reduce_rows<<<512, 256, 0, stream>>>(pminp, psump, loss);
    final_mean<<<1, 256, 0, stream>>>(loss, out);
}